// Round 1
// baseline (483.487 us; speedup 1.0000x reference)
//
#include <hip/hip_runtime.h>
#include <math.h>

// HebbyRNN: B=32, IN=128, H=1024, OUT=128
// chain of batched GEMVs (one dynamic weight matrix per sample) + tanh,
// then log_softmax head. Entirely HBM-bandwidth-bound (~570 MB of weights,
// each element used once).

#define B_SZ 32
#define IN_SZ 128
#define H_SZ 1024
#define OUT_SZ 128

// concat(x, hidden) -> combined [B, IN+H]
__global__ void concat_kernel(const float* __restrict__ x,
                              const float* __restrict__ h,
                              float* __restrict__ out) {
    int tid = blockIdx.x * blockDim.x + threadIdx.x;  // over 32*1152
    if (tid < B_SZ * (IN_SZ + H_SZ)) {
        int b = tid / (IN_SZ + H_SZ);
        int i = tid - b * (IN_SZ + H_SZ);
        out[tid] = (i < IN_SZ) ? x[b * IN_SZ + i] : h[b * H_SZ + (i - IN_SZ)];
    }
}

// Batched GEMV: out[b*O + o] = act( dot(W[b][o][:], v[b][:]) + bias[o] )
// One wave (64 lanes) per output row. W row-major [B, O, I], I % 4 == 0.
__global__ void gemv_kernel(const float* __restrict__ W,
                            const float* __restrict__ bias,
                            const float* __restrict__ v,
                            float* __restrict__ out,
                            int O, int I, int applyTanh) {
    int wave = blockIdx.x * (blockDim.x >> 6) + (threadIdx.x >> 6);
    int lane = threadIdx.x & 63;
    int row = wave;               // in [0, B*O)
    int b = row / O;
    int o = row - b * O;

    const float4* __restrict__ Wr = (const float4*)(W + (size_t)row * I);
    const float4* __restrict__ vr = (const float4*)(v + (size_t)b * I);
    int n4 = I >> 2;

    float sum = 0.f;
    for (int j = lane; j < n4; j += 64) {
        float4 w4 = Wr[j];
        float4 a4 = vr[j];
        sum += w4.x * a4.x + w4.y * a4.y + w4.z * a4.z + w4.w * a4.w;
    }
    // wave-64 reduction
    #pragma unroll
    for (int off = 32; off > 0; off >>= 1)
        sum += __shfl_down(sum, off, 64);

    if (lane == 0) {
        float r = sum + bias[o];
        out[row] = applyTanh ? tanhf(r) : r;
    }
}

// log_softmax over OUT=128 logits, one wave per batch row (2 logits/lane)
__global__ void logsoftmax_kernel(const float* __restrict__ logits,
                                  float* __restrict__ out) {
    int b = blockIdx.x;          // 32 blocks x 64 threads
    int lane = threadIdx.x;
    float v0 = logits[b * OUT_SZ + lane];
    float v1 = logits[b * OUT_SZ + 64 + lane];
    float m = fmaxf(v0, v1);
    #pragma unroll
    for (int off = 32; off > 0; off >>= 1)
        m = fmaxf(m, __shfl_xor(m, off, 64));
    float e = __expf(v0 - m) + __expf(v1 - m);
    #pragma unroll
    for (int off = 32; off > 0; off >>= 1)
        e += __shfl_xor(e, off, 64);
    float lse = m + logf(e);
    out[b * OUT_SZ + lane]      = v0 - lse;
    out[b * OUT_SZ + 64 + lane] = v1 - lse;
}

extern "C" void kernel_launch(void* const* d_in, const int* in_sizes, int n_in,
                              void* d_out, int out_size, void* d_ws, size_t ws_size,
                              hipStream_t stream) {
    const float* x      = (const float*)d_in[0];
    const float* hidden = (const float*)d_in[1];
    const float* W0 = (const float*)d_in[2];
    const float* b0 = (const float*)d_in[3];
    const float* W1 = (const float*)d_in[4];
    const float* b1 = (const float*)d_in[5];
    const float* W2 = (const float*)d_in[6];
    const float* b2 = (const float*)d_in[7];
    const float* Wh = (const float*)d_in[8];
    const float* bh = (const float*)d_in[9];
    const float* Wo = (const float*)d_in[10];
    const float* bo = (const float*)d_in[11];

    float* out_ls     = (float*)d_out;              // [32,128] log_softmax
    float* new_hidden = out_ls + B_SZ * OUT_SZ;     // [32,1024]

    float* ws = (float*)d_ws;
    float* combined = ws;                            // 32*1152 = 36864
    float* c1 = combined + B_SZ * (IN_SZ + H_SZ);    // 32*1024
    float* c2 = c1 + B_SZ * H_SZ;                    // 32*1024
    float* logits = c2 + B_SZ * H_SZ;                // 32*128

    // concat
    concat_kernel<<<(B_SZ * (IN_SZ + H_SZ) + 255) / 256, 256, 0, stream>>>(
        x, hidden, combined);

    // hidden-layer GEMVs: 32768 rows, 4 waves/block -> 8192 blocks
    const int blocksH = (B_SZ * H_SZ) / 4;   // 8192
    gemv_kernel<<<blocksH, 256, 0, stream>>>(W0, b0, combined, c1, H_SZ, IN_SZ + H_SZ, 1);
    gemv_kernel<<<blocksH, 256, 0, stream>>>(W1, b1, c1, c2, H_SZ, H_SZ, 1);
    gemv_kernel<<<blocksH, 256, 0, stream>>>(W2, b2, c2, c1, H_SZ, H_SZ, 1);  // c3 -> c1
    gemv_kernel<<<blocksH, 256, 0, stream>>>(Wh, bh, c1, new_hidden, H_SZ, H_SZ, 1);

    // output head: 4096 rows -> 1024 blocks
    gemv_kernel<<<(B_SZ * OUT_SZ) / 4, 256, 0, stream>>>(Wo, bo, c1, logits, OUT_SZ, H_SZ, 0);

    // log_softmax
    logsoftmax_kernel<<<B_SZ, 64, 0, stream>>>(logits, out_ls);
}

// Round 2
// 460.894 us; speedup vs baseline: 1.0490x; 1.0490x over previous
//
#include <hip/hip_runtime.h>
#include <math.h>

// HebbyRNN: B=32, IN=128, H=1024, OUT=128
// Chain of batched GEMVs (per-sample weight matrices) + tanh, log_softmax head.
// HBM-bound: ~570 MB of weights, each element used exactly once.
// R2: fused concat into layer0, fully-unrolled fixed-trip dot products,
//     fused Wh+Wo dispatch. 5 dispatches total.

#define B_SZ 32
#define IN_SZ 128
#define H_SZ 1024
#define OUT_SZ 128

__device__ __forceinline__ float wave_reduce(float s) {
    #pragma unroll
    for (int off = 32; off > 0; off >>= 1)
        s += __shfl_down(s, off, 64);
    return s;
}

__device__ __forceinline__ float dot4(float4 w, float4 a) {
    return w.x * a.x + w.y * a.y + w.z * a.z + w.w * a.w;
}

// Layer 0: W0 [B,1024,1152] * concat(x,hidden) -> tanh -> c1 [B,1024]
// One wave per row; I=1152 -> 288 float4 -> lanes do 4 each + lanes<32 do a 5th.
__global__ void gemv0_kernel(const float* __restrict__ W,
                             const float* __restrict__ bias,
                             const float* __restrict__ x,
                             const float* __restrict__ h,
                             float* __restrict__ out) {
    int wave = blockIdx.x * 4 + (threadIdx.x >> 6);   // 0..32767
    int lane = threadIdx.x & 63;
    int b = wave >> 10;
    int o = wave & 1023;

    const float4* __restrict__ Wr = (const float4*)(W + (size_t)wave * (IN_SZ + H_SZ));
    const float4* __restrict__ x4 = (const float4*)(x + b * IN_SZ);   // 32 float4
    const float4* __restrict__ h4 = (const float4*)(h + b * H_SZ);    // 256 float4

    float sum = 0.f;
    #pragma unroll
    for (int k = 0; k < 4; k++) {
        int j = lane + 64 * k;
        float4 w = Wr[j];
        float4 a = (j < 32) ? x4[j] : h4[j - 32];
        sum += dot4(w, a);
    }
    if (lane < 32) {
        int j = 256 + lane;
        float4 w = Wr[j];
        float4 a = h4[j - 32];
        sum += dot4(w, a);
    }
    sum = wave_reduce(sum);
    if (lane == 0) out[wave] = tanhf(sum + bias[o]);
}

// Middle layers: W [B,1024,1024] * v -> tanh -> out. One wave per row, I=1024.
__global__ void gemv_mid_kernel(const float* __restrict__ W,
                                const float* __restrict__ bias,
                                const float* __restrict__ v,
                                float* __restrict__ out) {
    int wave = blockIdx.x * 4 + (threadIdx.x >> 6);   // 0..32767
    int lane = threadIdx.x & 63;
    int b = wave >> 10;
    int o = wave & 1023;

    const float4* __restrict__ Wr = (const float4*)(W + (size_t)wave * H_SZ);
    const float4* __restrict__ vr = (const float4*)(v + b * H_SZ);

    float sum = 0.f;
    #pragma unroll
    for (int k = 0; k < 4; k++) {
        int j = lane + 64 * k;
        sum += dot4(Wr[j], vr[j]);
    }
    sum = wave_reduce(sum);
    if (lane == 0) out[wave] = tanhf(sum + bias[o]);
}

// Fused heads: rows [0, 32768) -> Wh (tanh -> new_hidden), rows [32768, 36864) -> Wo (logits)
__global__ void heads_kernel(const float* __restrict__ Wh,
                             const float* __restrict__ bh,
                             const float* __restrict__ Wo,
                             const float* __restrict__ bo,
                             const float* __restrict__ v,
                             float* __restrict__ new_hidden,
                             float* __restrict__ logits) {
    int wave = blockIdx.x * 4 + (threadIdx.x >> 6);   // 0..36863
    int lane = threadIdx.x & 63;
    bool isO = wave >= B_SZ * H_SZ;
    int r = isO ? wave - B_SZ * H_SZ : wave;
    int b = isO ? (r >> 7) : (r >> 10);

    const float* Wbase = isO ? (Wo + (size_t)r * H_SZ) : (Wh + (size_t)r * H_SZ);
    const float4* __restrict__ Wr = (const float4*)Wbase;
    const float4* __restrict__ vr = (const float4*)(v + b * H_SZ);

    float sum = 0.f;
    #pragma unroll
    for (int k = 0; k < 4; k++) {
        int j = lane + 64 * k;
        sum += dot4(Wr[j], vr[j]);
    }
    sum = wave_reduce(sum);
    if (lane == 0) {
        if (isO) {
            int o = r & (OUT_SZ - 1);
            logits[r] = sum + bo[o];
        } else {
            int o = r & (H_SZ - 1);
            new_hidden[r] = tanhf(sum + bh[o]);
        }
    }
}

// log_softmax over OUT=128 logits, one wave per batch row (2 logits/lane)
__global__ void logsoftmax_kernel(const float* __restrict__ logits,
                                  float* __restrict__ out) {
    int b = blockIdx.x;          // 32 blocks x 64 threads
    int lane = threadIdx.x;
    float v0 = logits[b * OUT_SZ + lane];
    float v1 = logits[b * OUT_SZ + 64 + lane];
    float m = fmaxf(v0, v1);
    #pragma unroll
    for (int off = 32; off > 0; off >>= 1)
        m = fmaxf(m, __shfl_xor(m, off, 64));
    float e = __expf(v0 - m) + __expf(v1 - m);
    #pragma unroll
    for (int off = 32; off > 0; off >>= 1)
        e += __shfl_xor(e, off, 64);
    float lse = m + logf(e);
    out[b * OUT_SZ + lane]      = v0 - lse;
    out[b * OUT_SZ + 64 + lane] = v1 - lse;
}

extern "C" void kernel_launch(void* const* d_in, const int* in_sizes, int n_in,
                              void* d_out, int out_size, void* d_ws, size_t ws_size,
                              hipStream_t stream) {
    const float* x      = (const float*)d_in[0];
    const float* hidden = (const float*)d_in[1];
    const float* W0 = (const float*)d_in[2];
    const float* b0 = (const float*)d_in[3];
    const float* W1 = (const float*)d_in[4];
    const float* b1 = (const float*)d_in[5];
    const float* W2 = (const float*)d_in[6];
    const float* b2 = (const float*)d_in[7];
    const float* Wh = (const float*)d_in[8];
    const float* bh = (const float*)d_in[9];
    const float* Wo = (const float*)d_in[10];
    const float* bo = (const float*)d_in[11];

    float* out_ls     = (float*)d_out;              // [32,128] log_softmax
    float* new_hidden = out_ls + B_SZ * OUT_SZ;     // [32,1024]

    float* ws = (float*)d_ws;
    float* c1 = ws;                                  // 32*1024
    float* c2 = c1 + B_SZ * H_SZ;                    // 32*1024
    float* logits = c2 + B_SZ * H_SZ;                // 32*128

    const int blocksH = (B_SZ * H_SZ) / 4;           // 8192 blocks of 256
    gemv0_kernel<<<blocksH, 256, 0, stream>>>(W0, b0, x, hidden, c1);
    gemv_mid_kernel<<<blocksH, 256, 0, stream>>>(W1, b1, c1, c2);
    gemv_mid_kernel<<<blocksH, 256, 0, stream>>>(W2, b2, c2, c1);

    const int blocksHeads = (B_SZ * H_SZ + B_SZ * OUT_SZ) / 4;  // 9216
    heads_kernel<<<blocksHeads, 256, 0, stream>>>(Wh, bh, Wo, bo, c1, new_hidden, logits);

    logsoftmax_kernel<<<B_SZ, 64, 0, stream>>>(logits, out_ls);
}